// Round 4
// baseline (178.259 us; speedup 1.0000x reference)
//
#include <hip/hip_runtime.h>

typedef float f4 __attribute__((ext_vector_type(4)));

// One wave per 8 tokens. Lane i owns d-positions {4i + 256c : c=0..3} of the
// 1024-wide row -> global_load_dwordx4, 64 lanes x 16B = 1KB coalesced/inst.
// All 9 weight rows live in 144 VGPRs... compiler shrinks working set; at
// VGPR<=128 we get 4 waves/SIMD. 4096 waves = 16 waves/CU (50% occupancy)
// covers per-token vmcnt stalls. Cross-lane reduce via DPP (VALU pipe, no
// LDS, no barriers). 3-deep token ring = 12KB in flight/wave.
#define TPW 8
#define PF  3

template <int CTRL>
__device__ __forceinline__ float dpp_add(float x) {
  int yi = __builtin_amdgcn_update_dpp(0, __float_as_int(x), CTRL, 0xF, 0xF, true);
  return x + __int_as_float(yi);
}

// After this, lane 63 holds the full 64-lane sum (other lanes hold partials).
__device__ __forceinline__ float wave_sum63(float x) {
  x = dpp_add<0x111>(x);  // row_shr:1
  x = dpp_add<0x112>(x);  // row_shr:2
  x = dpp_add<0x114>(x);  // row_shr:4
  x = dpp_add<0x118>(x);  // row_shr:8  -> lane 16r+15 = sum of row r
  x = dpp_add<0x142>(x);  // row_bcast:15
  x = dpp_add<0x143>(x);  // row_bcast:31 -> lane 63 = total
  return x;
}

__global__ __launch_bounds__(256, 4)
void moa_kernel(const float* __restrict__ tok,
                const float* __restrict__ Wq,
                const float* __restrict__ Wk,
                const float* __restrict__ Wv,
                float* __restrict__ out,
                int n_tokens) {
  const int lane = threadIdx.x & 63;
  const int wid  = (blockIdx.x << 2) | (threadIdx.x >> 6);
  const int base = lane << 2;

  // ---- 9 weight vectors -> VGPRs (coalesced, L2-resident broadcast) ----
  f4 w[9][4];
  const float* Wp[3] = {Wq, Wk, Wv};
#pragma unroll
  for (int m = 0; m < 3; ++m)
#pragma unroll
    for (int e = 0; e < 3; ++e)
#pragma unroll
      for (int c = 0; c < 4; ++c)
        w[m * 3 + e][c] = *(const f4*)(Wp[m] + e * 1024 + c * 256 + base);

  const int t0 = wid * TPW;
  if (t0 >= n_tokens) return;

  // ---- prologue: fill 3-deep ring (grid divides n_tokens exactly) ----
  f4 buf[PF][4];
#pragma unroll
  for (int i = 0; i < PF; ++i) {
    const float* p = tok + (size_t)(t0 + i) * 1024 + base;
#pragma unroll
    for (int c = 0; c < 4; ++c) buf[i][c] = *(const f4*)(p + c * 256);
  }

  float outv = 0.0f;

#pragma unroll
  for (int i = 0; i < TPW; ++i) {
    const int s = i % PF;                 // compile-time after unroll
    f4 x0 = buf[s][0], x1 = buf[s][1], x2 = buf[s][2], x3 = buf[s][3];

    // prefetch token i+PF into the freed slot (issued before the compute)
    if (i + PF < TPW) {
      const float* p = tok + (size_t)(t0 + i + PF) * 1024 + base;
#pragma unroll
      for (int c = 0; c < 4; ++c) buf[s][c] = *(const f4*)(p + c * 256);
    }

    // ---- 9 partial dots (packed FMAs) + DPP wave reduction ----
    float s9[9];
#pragma unroll
    for (int j = 0; j < 9; ++j) {
      f4 a = x0 * w[j][0];
      a += x1 * w[j][1];
      a += x2 * w[j][2];
      a += x3 * w[j][3];
      s9[j] = wave_sum63((a.x + a.y) + (a.z + a.w));
    }

    // ---- tiny softmax chain (valid in lane 63; others compute garbage) ----
    float lg[3];
#pragma unroll
    for (int e = 0; e < 3; ++e) {
      float e0 = __expf(s9[e] * s9[3]);
      float e1 = __expf(s9[e] * s9[4]);
      float e2 = __expf(s9[e] * s9[5]);
      float den = (e0 + e1) + e2;
      float num = e0 * s9[6] + e1 * s9[7] + e2 * s9[8];
      lg[e] = num * __builtin_amdgcn_rcpf(den);
    }
    float u0 = __expf(lg[0]);
    float u1 = __expf(lg[1]);
    float u2 = __expf(lg[2]);
    float rs = __builtin_amdgcn_rcpf((u0 + u1) + u2);

    // broadcast lane 63's final three weights to all lanes
    float r0 = __int_as_float(__builtin_amdgcn_readlane(__float_as_int(u0 * rs), 63));
    float r1 = __int_as_float(__builtin_amdgcn_readlane(__float_as_int(u1 * rs), 63));
    float r2 = __int_as_float(__builtin_amdgcn_readlane(__float_as_int(u2 * rs), 63));

    // collect into the per-lane output slot (token i -> lanes 3i..3i+2)
    const int rel = lane - 3 * i;
    outv = (rel == 0) ? r0 : outv;
    outv = (rel == 1) ? r1 : outv;
    outv = (rel == 2) ? r2 : outv;
  }

  // ---- one coalesced 96B store per wave ----
  const int oidx = t0 * 3 + lane;
  if (lane < 3 * TPW) out[oidx] = outv;
}

extern "C" void kernel_launch(void* const* d_in, const int* in_sizes, int n_in,
                              void* d_out, int out_size, void* d_ws, size_t ws_size,
                              hipStream_t stream) {
  const float* tok = (const float*)d_in[0];
  const float* Wq  = (const float*)d_in[1];
  const float* Wk  = (const float*)d_in[2];
  const float* Wv  = (const float*)d_in[3];
  float* out = (float*)d_out;

  const int n_tokens = in_sizes[0] / 1024;           // 32768
  const int waves    = (n_tokens + TPW - 1) / TPW;   // 4096
  const int blocks   = (waves + 3) / 4;              // 1024

  hipLaunchKernelGGL(moa_kernel, dim3(blocks), dim3(256), 0, stream,
                     tok, Wq, Wk, Wv, out, n_tokens);
}

// Round 5
// 28.079 us; speedup vs baseline: 6.3486x; 6.3486x over previous
//
#include <hip/hip_runtime.h>

typedef float f4 __attribute__((ext_vector_type(4)));

// One wave per 8 tokens. Lane i owns d-positions {4i + 256c : c=0..3} of the
// 1024-wide row -> global_load_dwordx4, 64 lanes x 16B = 1KB coalesced/inst.
// All 9 weight rows live in ~144 VGPRs, loaded once per wave (L2 broadcast).
// VGPR ~108 permits 4 waves/SIMD; grid = 4096 waves = 16 waves/CU gives the
// TLP to hide per-token vmcnt stalls. NOTE: do NOT raise min-waves in
// __launch_bounds__ -- (256,4) made the compiler target 64 VGPRs and
// rematerialize the weights from global every token (FETCH 66MB -> 450MB).
// Cross-lane reduce via DPP on the VALU pipe; no LDS, no barriers.
#define TPW 8
#define PF  3

template <int CTRL>
__device__ __forceinline__ float dpp_add(float x) {
  int yi = __builtin_amdgcn_update_dpp(0, __float_as_int(x), CTRL, 0xF, 0xF, true);
  return x + __int_as_float(yi);
}

// After this, lane 63 holds the full 64-lane sum (other lanes hold partials).
__device__ __forceinline__ float wave_sum63(float x) {
  x = dpp_add<0x111>(x);  // row_shr:1
  x = dpp_add<0x112>(x);  // row_shr:2
  x = dpp_add<0x114>(x);  // row_shr:4
  x = dpp_add<0x118>(x);  // row_shr:8  -> lane 16r+15 = sum of row r
  x = dpp_add<0x142>(x);  // row_bcast:15
  x = dpp_add<0x143>(x);  // row_bcast:31 -> lane 63 = total
  return x;
}

__global__ __launch_bounds__(256, 2)
void moa_kernel(const float* __restrict__ tok,
                const float* __restrict__ Wq,
                const float* __restrict__ Wk,
                const float* __restrict__ Wv,
                float* __restrict__ out,
                int n_tokens) {
  const int lane = threadIdx.x & 63;
  const int wid  = (blockIdx.x << 2) | (threadIdx.x >> 6);
  const int base = lane << 2;

  // ---- 9 weight vectors -> VGPRs (coalesced, L2-resident broadcast) ----
  f4 w[9][4];
  const float* Wp[3] = {Wq, Wk, Wv};
#pragma unroll
  for (int m = 0; m < 3; ++m)
#pragma unroll
    for (int e = 0; e < 3; ++e)
#pragma unroll
      for (int c = 0; c < 4; ++c)
        w[m * 3 + e][c] = *(const f4*)(Wp[m] + e * 1024 + c * 256 + base);

  const int t0 = wid * TPW;
  if (t0 >= n_tokens) return;

  // ---- prologue: fill 3-deep ring (grid divides n_tokens exactly) ----
  f4 buf[PF][4];
#pragma unroll
  for (int i = 0; i < PF; ++i) {
    const float* p = tok + (size_t)(t0 + i) * 1024 + base;
#pragma unroll
    for (int c = 0; c < 4; ++c) buf[i][c] = *(const f4*)(p + c * 256);
  }

  float outv = 0.0f;

#pragma unroll
  for (int i = 0; i < TPW; ++i) {
    const int s = i % PF;                 // compile-time after unroll
    f4 x0 = buf[s][0], x1 = buf[s][1], x2 = buf[s][2], x3 = buf[s][3];

    // prefetch token i+PF into the freed slot (issued before the compute)
    if (i + PF < TPW) {
      const float* p = tok + (size_t)(t0 + i + PF) * 1024 + base;
#pragma unroll
      for (int c = 0; c < 4; ++c) buf[s][c] = *(const f4*)(p + c * 256);
    }

    // ---- 9 partial dots (packed FMAs) + DPP wave reduction ----
    float s9[9];
#pragma unroll
    for (int j = 0; j < 9; ++j) {
      f4 a = x0 * w[j][0];
      a += x1 * w[j][1];
      a += x2 * w[j][2];
      a += x3 * w[j][3];
      s9[j] = wave_sum63((a.x + a.y) + (a.z + a.w));
    }

    // ---- tiny softmax chain (valid in lane 63; others compute garbage) ----
    float lg[3];
#pragma unroll
    for (int e = 0; e < 3; ++e) {
      float e0 = __expf(s9[e] * s9[3]);
      float e1 = __expf(s9[e] * s9[4]);
      float e2 = __expf(s9[e] * s9[5]);
      float den = (e0 + e1) + e2;
      float num = e0 * s9[6] + e1 * s9[7] + e2 * s9[8];
      lg[e] = num * __builtin_amdgcn_rcpf(den);
    }
    float u0 = __expf(lg[0]);
    float u1 = __expf(lg[1]);
    float u2 = __expf(lg[2]);
    float rs = __builtin_amdgcn_rcpf((u0 + u1) + u2);

    // broadcast lane 63's final three weights to all lanes
    float r0 = __int_as_float(__builtin_amdgcn_readlane(__float_as_int(u0 * rs), 63));
    float r1 = __int_as_float(__builtin_amdgcn_readlane(__float_as_int(u1 * rs), 63));
    float r2 = __int_as_float(__builtin_amdgcn_readlane(__float_as_int(u2 * rs), 63));

    // collect into the per-lane output slot (token i -> lanes 3i..3i+2)
    const int rel = lane - 3 * i;
    outv = (rel == 0) ? r0 : outv;
    outv = (rel == 1) ? r1 : outv;
    outv = (rel == 2) ? r2 : outv;
  }

  // ---- one coalesced 96B store per wave ----
  const int oidx = t0 * 3 + lane;
  if (lane < 3 * TPW) out[oidx] = outv;
}

extern "C" void kernel_launch(void* const* d_in, const int* in_sizes, int n_in,
                              void* d_out, int out_size, void* d_ws, size_t ws_size,
                              hipStream_t stream) {
  const float* tok = (const float*)d_in[0];
  const float* Wq  = (const float*)d_in[1];
  const float* Wk  = (const float*)d_in[2];
  const float* Wv  = (const float*)d_in[3];
  float* out = (float*)d_out;

  const int n_tokens = in_sizes[0] / 1024;           // 32768
  const int waves    = (n_tokens + TPW - 1) / TPW;   // 4096
  const int blocks   = (waves + 3) / 4;              // 1024

  hipLaunchKernelGGL(moa_kernel, dim3(blocks), dim3(256), 0, stream,
                     tok, Wq, Wk, Wv, out, n_tokens);
}